// Round 6
// baseline (336.540 us; speedup 1.0000x reference)
//
#include <hip/hip_runtime.h>
#include <math.h>

#define U 128
#define GAMMA 28
#define TB 16        // batch rows per block (one MFMA row-group)
#define NT 512       // 8 waves
#define NSTEPS 75    // 48 encoder + 27 feedback

typedef _Float16 half8 __attribute__((ext_vector_type(8)));
typedef float floatx4 __attribute__((ext_vector_type(4)));

__device__ __forceinline__ float sigmoid_f(float x) { return 1.0f / (1.0f + __expf(-x)); }
__device__ __forceinline__ float tanh_f(float x)    { return 1.0f - 2.0f / (1.0f + __expf(2.0f * x)); }
__device__ __forceinline__ float softplus_f(float x) {
    return fmaxf(x, 0.0f) + log1pf(__expf(-fabsf(x)));
}

__global__ __launch_bounds__(NT, 4) void fib_rnn_kernel(
    const float* __restrict__ inp,      // (B,49,1)
    const float* __restrict__ Kw,       // (1,384)
    const float* __restrict__ Rw,       // (128,384)
    const float* __restrict__ bias,     // (2,384)
    const float* __restrict__ dv_loc,   // (258)
    const float* __restrict__ dv_rho,   // (258)
    const float* __restrict__ dv_eps,   // (28,258)
    const float* __restrict__ samp,     // (27,B,1)
    float* __restrict__ out,            // (B,28,2)
    int B)
{
    // h (fp16), double-buffered, MFMA A-fragment order:
    // element (b, j) at half-index ((j>>3)*16 + b)*8 + (j&7)
    __shared__ __align__(16) _Float16 hA[2][2048];
    __shared__ float in_lds[TB][48];
    __shared__ __align__(16) _Float16 epsD[2 * 28 * 128];  // [n][s][k] deinterleaved fp16
    __shared__ __align__(16) _Float16 locD[2 * 128];       // [n][k]
    __shared__ __align__(16) _Float16 scaD[2 * 128];       // [n][k]
    __shared__ float epsB[28 * 2];                         // dense bias eps rows (fp32)
    __shared__ float samp_lds[27 * 16];

    const int tid  = threadIdx.x;
    const int wv   = tid >> 6;          // wave 0..7
    const int lane = tid & 63;
    const int q    = lane >> 4;         // quad 0..3
    const int m16  = lane & 15;
    const int r0   = q * 4;             // first batch row of this lane's C regs
    const int b0   = blockIdx.x * TB;
    const int j    = wv * 16 + m16;     // this lane's gate column (0..127)
    const int nsel = (m16 < 2) ? m16 : 0;

    // ---- one-time staging
    for (int i = tid; i < TB * 48; i += NT) {
        int bl = i / 48, tt = i - bl * 48;
        in_lds[bl][tt] = inp[(size_t)(b0 + bl) * 49 + tt];
    }
    for (int i = tid; i < 4096; i += NT) (&hA[0][0])[i] = (_Float16)0.f;
    const float Cc = 0.5413248546f;   // log(expm1(1))
    for (int i = tid; i < 28 * 258; i += NT) {
        int s = i / 258, t = i - 258 * s;
        float v = dv_eps[i];
        if (t < 256) epsD[(t & 1) * 3584 + s * 128 + (t >> 1)] = (_Float16)v;
        else         epsB[s * 2 + (t - 256)] = v;
    }
    for (int i = tid; i < 256; i += NT) {
        int k = i >> 1, n = i & 1;
        locD[n * 128 + k] = (_Float16)dv_loc[i];
        scaD[n * 128 + k] = (_Float16)(1e-5f + 0.02f * softplus_f(Cc + dv_rho[i]));
    }
    for (int i = tid; i < 27 * 16; i += NT) {
        int s = i >> 4, bl = i & 15;
        samp_lds[i] = samp[(size_t)s * B + b0 + bl];
    }

    // ---- stationary R fragments (fp16). Wave wv owns n-tiles {wv, wv+8, wv+16}
    half8 Rb[3][4];
    {
        const int tiles[3] = {wv, wv + 8, wv + 16};
        #pragma unroll
        for (int t = 0; t < 3; ++t) {
            const int c = tiles[t] * 16 + m16;
            #pragma unroll
            for (int kt = 0; kt < 4; ++kt) {
                #pragma unroll
                for (int e = 0; e < 8; ++e)
                    Rb[t][kt][e] = (_Float16)Rw[(size_t)(kt * 32 + q * 8 + e) * 384 + c];
            }
        }
    }

    // per-lane gate constants for column j
    const float Kz  = Kw[j], Kr = Kw[j + U], Kh = Kw[j + 2 * U];
    const float bz  = bias[j]         + bias[384 + j];
    const float br  = bias[j + U]     + bias[384 + j + U];
    const float bhx = bias[j + 2 * U];
    const float bhh = bias[384 + j + 2 * U];

    float locB_l = 0.f, scaB_l = 0.f;
    if (m16 < 2) {
        locB_l = dv_loc[256 + m16];
        scaB_l = 1e-5f + 0.02f * softplus_f(Cc + dv_rho[256 + m16]);
    }

    float hprev[4] = {0.f, 0.f, 0.f, 0.f};
    float xfb[4]   = {0.f, 0.f, 0.f, 0.f};   // feedback inputs (valid from step 48)

    __syncthreads();

    int cur = 0;
    for (int step = 0; step < NSTEPS; ++step) {
        // ---- recurrent matmul: preact[16][384] = h[16][128] @ R  (fp16 MFMA)
        floatx4 acc[3];
        #pragma unroll
        for (int t = 0; t < 3; ++t) acc[t] = (floatx4){0.f, 0.f, 0.f, 0.f};

        #pragma unroll
        for (int kt = 0; kt < 4; ++kt) {
            const half8 Ah = *reinterpret_cast<const half8*>(&hA[cur][kt * 512 + lane * 8]);
            #pragma unroll
            for (int t = 0; t < 3; ++t)
                acc[t] = __builtin_amdgcn_mfma_f32_16x16x32_f16(Ah, Rb[t][kt], acc[t], 0, 0, 0);
        }

        // ---- gates (lane owns rows r0..r0+3, col j); h state fp32 in regs
        float hn[4];
        #pragma unroll
        for (int i = 0; i < 4; ++i) {
            const float x = (step < 48) ? in_lds[r0 + i][step] : xfb[i];
            const float z  = sigmoid_f(acc[0][i] + fmaf(x, Kz, bz));
            const float r  = sigmoid_f(acc[1][i] + fmaf(x, Kr, br));
            const float hh = tanh_f(fmaf(x, Kh, bhx) + r * (acc[2][i] + bhh));
            hn[i] = z * hprev[i] + (1.f - z) * hh;
            hprev[i] = hn[i];
        }

        // write new h into the other buffer (no pre-barrier needed: disjoint buffer)
        const int nxt = cur ^ 1;
        #pragma unroll
        for (int i = 0; i < 4; ++i) {
            const int idx = ((j >> 3) * 16 + (r0 + i)) * 8 + (j & 7);
            hA[nxt][idx] = (_Float16)hn[i];
        }
        __syncthreads();   // the ONLY barrier per step: h[nxt] complete & visible

        const int s = step - 47;
        if (s >= 0) {
            // ---- dense_var via one MFMA n-tile: x2[16][2] = h_new @ W  (cols >=2 zeroed)
            floatx4 accd = (floatx4){0.f, 0.f, 0.f, 0.f};
            const half8 hz = {};
            #pragma unroll
            for (int kt = 0; kt < 4; ++kt) {
                const int ko = kt * 32 + q * 8;
                const half8 ev = *reinterpret_cast<const half8*>(&epsD[nsel * 3584 + s * 128 + ko]);
                const half8 lv = *reinterpret_cast<const half8*>(&locD[nsel * 128 + ko]);
                const half8 sv = *reinterpret_cast<const half8*>(&scaD[nsel * 128 + ko]);
                half8 w = lv + sv * ev;
                if (m16 >= 2) w = hz;
                const half8 Ah = *reinterpret_cast<const half8*>(&hA[nxt][kt * 512 + lane * 8]);
                accd = __builtin_amdgcn_mfma_f32_16x16x32_f16(Ah, w, accd, 0, 0, 0);
            }
            const float wb = fmaf(scaB_l, epsB[s * 2 + nsel], locB_l);
            const int ssamp = (s < GAMMA - 1) ? s : 0;   // clamp for bounds (y unused at s=27)

            float x20[4], sc[4], yv[4];
            #pragma unroll
            for (int i = 0; i < 4; ++i) {
                const float mine = accd[i] + wb;
                const float oth  = __shfl_xor(mine, 1, 64);
                x20[i] = (m16 & 1) ? oth  : mine;
                const float x21 = (m16 & 1) ? mine : oth;
                sc[i]  = 1e-5f + 0.05f * softplus_f(Cc + x21);
                yv[i]  = fmaf(sc[i], samp_lds[ssamp * 16 + r0 + i], x20[i]);
            }
            // stores: wave 0, lanes m16<2 (col0 -> loc, col1 -> scale)
            if (wv == 0 && m16 < 2) {
                #pragma unroll
                for (int i = 0; i < 4; ++i) {
                    const size_t ob = ((size_t)(b0 + r0 + i) * GAMMA + s) * 2 + m16;
                    out[ob] = (m16 == 0) ? x20[i] : sc[i];
                }
            }
            // feedback distribution: row r0+i's y lives on lane (q*16); intra-wave shuffle
            if (s < GAMMA - 1) {
                #pragma unroll
                for (int i = 0; i < 4; ++i)
                    xfb[i] = __shfl(yv[i], lane & 48, 64);
            }
        }
        cur = nxt;
    }
}

extern "C" void kernel_launch(void* const* d_in, const int* in_sizes, int n_in,
                              void* d_out, int out_size, void* d_ws, size_t ws_size,
                              hipStream_t stream) {
    const float* inp    = (const float*)d_in[0];
    const float* Kw     = (const float*)d_in[1];
    const float* Rw     = (const float*)d_in[2];
    const float* bias   = (const float*)d_in[3];
    const float* dv_loc = (const float*)d_in[4];
    const float* dv_rho = (const float*)d_in[5];
    const float* dv_eps = (const float*)d_in[6];
    const float* samp   = (const float*)d_in[7];
    float* out = (float*)d_out;
    const int B = in_sizes[0] / 49;   // 8192
    dim3 grid(B / TB), block(NT);
    hipLaunchKernelGGL(fib_rnn_kernel, grid, block, 0, stream,
                       inp, Kw, Rw, bias, dv_loc, dv_rho, dv_eps, samp, out, B);
}

// Round 7
// 244.901 us; speedup vs baseline: 1.3742x; 1.3742x over previous
//
#include <hip/hip_runtime.h>
#include <math.h>

#define U 128
#define GAMMA 28
#define TB 16        // batch rows per block (one MFMA tile N-dim)
#define NT 512       // 8 waves
#define NSTEPS 75    // 48 encoder + 27 feedback
#define HSTR 136     // halves per hA row: 128 + 8 pad (272 B, 16B-aligned, odd*4 dwords)
#define ESTR 260     // floats per wfin row: 258 -> 260 (1040 B, 16B-aligned)

typedef _Float16 half8 __attribute__((ext_vector_type(8)));
typedef _Float16 half4 __attribute__((ext_vector_type(4)));
typedef float floatx4 __attribute__((ext_vector_type(4)));

__device__ __forceinline__ float sigmoid_f(float x) { return 1.0f / (1.0f + __expf(-x)); }
__device__ __forceinline__ float tanh_f(float x)    { return 1.0f - 2.0f / (1.0f + __expf(2.0f * x)); }
__device__ __forceinline__ float softplus_f(float x) {
    // max(x,0) + log1p(exp(-|x|)); e in (0,1] so plain logf(1+e) is exact enough
    return fmaxf(x, 0.0f) + __logf(1.0f + __expf(-fabsf(x)));
}

__global__ __launch_bounds__(NT, 4) void fib_rnn_kernel(
    const float* __restrict__ inp,      // (B,49,1)
    const float* __restrict__ Kw,       // (1,384)
    const float* __restrict__ Rw,       // (128,384)
    const float* __restrict__ bias,     // (2,384)
    const float* __restrict__ dv_loc,   // (258)
    const float* __restrict__ dv_rho,   // (258)
    const float* __restrict__ dv_eps,   // (28,258)
    const float* __restrict__ samp,     // (27,B,1)
    float* __restrict__ out,            // (B,28,2)
    int B)
{
    // h[batch][k] fp16, double-buffered, row-major with padded stride
    __shared__ __align__(16) _Float16 hA[2][TB * HSTR];
    __shared__ __align__(16) float wfin[GAMMA * ESTR];   // per-step dense weights [s][2j+n]
    __shared__ float in_lds[TB * 49];
    __shared__ float samp_lds[27 * TB];
    __shared__ float wsum[2][8][TB][2];                  // [parity][wave][row][n]
    __shared__ float epsB[GAMMA][2];

    const int tid  = threadIdx.x;
    const int wv   = tid >> 6;          // wave 0..7
    const int lane = tid & 63;
    const int q    = lane >> 4;         // quad 0..3
    const int m16  = lane & 15;         // this lane's batch row
    const int j0   = wv * 16 + q * 4;   // first of this lane's 4 gate columns
    const int b0   = blockIdx.x * TB;

    const float Cc = 0.5413248546f;     // log(expm1(1))

    // ---- one-time staging
    for (int i = tid; i < TB * 48; i += NT) {
        int bl = i / 48, tt = i - bl * 48;
        in_lds[bl * 49 + tt] = inp[(size_t)(b0 + bl) * 49 + tt];
    }
    for (int i = tid; i < 2 * TB * HSTR; i += NT) (&hA[0][0])[i] = (_Float16)0.f;
    for (int i = tid; i < GAMMA * 258; i += NT) {
        int s = i / 258, t = i - 258 * s;
        float v = dv_eps[i];
        if (t < 256) {
            float sc = 1e-5f + 0.02f * softplus_f(Cc + dv_rho[t]);
            wfin[s * ESTR + t] = fmaf(sc, v, dv_loc[t]);
        } else {
            epsB[s][t - 256] = v;
        }
    }
    for (int i = tid; i < 27 * TB; i += NT) {
        int s = i >> 4, bl = i & 15;
        samp_lds[i] = samp[(size_t)s * B + b0 + bl];
    }

    // ---- stationary R^T fragments (A operand, fp16). Wave wv: tiles {wv, wv+8, wv+16}
    // A[m=lane&15][k=q*8+e+kt*32] = R[k][tile*16+m16]
    half8 Rb[3][4];
    {
        const int tiles[3] = {wv, wv + 8, wv + 16};
        #pragma unroll
        for (int t = 0; t < 3; ++t) {
            const int c = tiles[t] * 16 + m16;
            #pragma unroll
            for (int kt = 0; kt < 4; ++kt) {
                #pragma unroll
                for (int e = 0; e < 8; ++e)
                    Rb[t][kt][e] = (_Float16)Rw[(size_t)(kt * 32 + q * 8 + e) * 384 + c];
            }
        }
    }

    // per-lane gate constants for columns j0..j0+3
    float Kz4[4], Kr4[4], Kh4[4], bz4[4], br4[4], bhx4[4], bhh4[4];
    #pragma unroll
    for (int i = 0; i < 4; ++i) {
        const int j = j0 + i;
        Kz4[i]  = Kw[j]; Kr4[i] = Kw[j + U]; Kh4[i] = Kw[j + 2 * U];
        bz4[i]  = bias[j]         + bias[384 + j];
        br4[i]  = bias[j + U]     + bias[384 + j + U];
        bhx4[i] = bias[j + 2 * U];
        bhh4[i] = bias[384 + j + 2 * U];
    }
    const float wbl0 = dv_loc[256], wbl1 = dv_loc[257];
    const float wbs0 = 1e-5f + 0.02f * softplus_f(Cc + dv_rho[256]);
    const float wbs1 = 1e-5f + 0.02f * softplus_f(Cc + dv_rho[257]);

    float hprev[4] = {0.f, 0.f, 0.f, 0.f};   // h state: row m16, cols j0..j0+3

    __syncthreads();

    int cur = 0;
    for (int step = 0; step < NSTEPS; ++step) {
        // ---- recurrent matmul: preact[384][16] = R^T @ h^T   (A=R^T stationary, B=h)
        floatx4 acc[3];
        #pragma unroll
        for (int t = 0; t < 3; ++t) acc[t] = (floatx4){0.f, 0.f, 0.f, 0.f};
        #pragma unroll
        for (int kt = 0; kt < 4; ++kt) {
            const half8 Bh = *reinterpret_cast<const half8*>(&hA[cur][m16 * HSTR + kt * 32 + q * 8]);
            #pragma unroll
            for (int t = 0; t < 3; ++t)
                acc[t] = __builtin_amdgcn_mfma_f32_16x16x32_f16(Rb[t][kt], Bh, acc[t], 0, 0, 0);
        }

        // ---- phase A (fb): finish previous step's dense_var; produce this lane's y
        float yv = 0.f;
        if (step >= 48) {
            const int sp = step - 48;
            const int pb = sp & 1;
            float sx = 0.f, sy = 0.f;
            #pragma unroll
            for (int w = 0; w < 8; ++w) {
                const float2 f = *reinterpret_cast<const float2*>(&wsum[pb][w][m16][0]);
                sx += f.x; sy += f.y;
            }
            const float x20 = sx + fmaf(wbs0, epsB[sp][0], wbl0);
            const float x21 = sy + fmaf(wbs1, epsB[sp][1], wbl1);
            const float sc  = 1e-5f + 0.05f * softplus_f(Cc + x21);
            yv = fmaf(sc, samp_lds[sp * 16 + m16], x20);
            if (wv == 0 && q == 0)
                *reinterpret_cast<float2*>(&out[((size_t)(b0 + m16) * GAMMA + sp) * 2]) =
                    make_float2(x20, sc);
        }

        // ---- gates: lane owns (row m16, cols j0..j0+3); fp32 state in regs
        const float x = (step < 48) ? in_lds[m16 * 49 + step] : yv;
        float hn[4];
        #pragma unroll
        for (int i = 0; i < 4; ++i) {
            const float z  = sigmoid_f(acc[0][i] + fmaf(x, Kz4[i], bz4[i]));
            const float r  = sigmoid_f(acc[1][i] + fmaf(x, Kr4[i], br4[i]));
            const float hh = tanh_f(fmaf(x, Kh4[i], bhx4[i]) + r * (acc[2][i] + bhh4[i]));
            hn[i] = z * hprev[i] + (1.f - z) * hh;
            hprev[i] = hn[i];
        }
        // one contiguous 8B store into the other h buffer
        half4 hp;
        #pragma unroll
        for (int i = 0; i < 4; ++i) hp[i] = (_Float16)hn[i];
        *reinterpret_cast<half4*>(&hA[cur ^ 1][m16 * HSTR + j0]) = hp;

        // ---- dense_var partials for this step (consumed next step in phase A)
        if (step >= 47) {
            const int s = step - 47;
            const float4 wa = *reinterpret_cast<const float4*>(&wfin[s * ESTR + 2 * j0]);
            const float4 wb = *reinterpret_cast<const float4*>(&wfin[s * ESTR + 2 * j0 + 4]);
            float pv0 = hn[0] * wa.x + hn[1] * wa.z + hn[2] * wb.x + hn[3] * wb.z;
            float pv1 = hn[0] * wa.y + hn[1] * wa.w + hn[2] * wb.y + hn[3] * wb.w;
            pv0 += __shfl_xor(pv0, 16, 64);  pv1 += __shfl_xor(pv1, 16, 64);
            pv0 += __shfl_xor(pv0, 32, 64);  pv1 += __shfl_xor(pv1, 32, 64);
            if (q == 0)
                *reinterpret_cast<float2*>(&wsum[s & 1][wv][m16][0]) = make_float2(pv0, pv1);
        }

        __syncthreads();   // the ONLY barrier: h[nxt] + wsum(s) visible
        cur ^= 1;
    }

    // ---- final output s = 27 (parity 1)
    if (wv == 0 && q == 0) {
        float sx = 0.f, sy = 0.f;
        #pragma unroll
        for (int w = 0; w < 8; ++w) {
            const float2 f = *reinterpret_cast<const float2*>(&wsum[1][w][m16][0]);
            sx += f.x; sy += f.y;
        }
        const float x20 = sx + fmaf(wbs0, epsB[27][0], wbl0);
        const float x21 = sy + fmaf(wbs1, epsB[27][1], wbl1);
        const float sc  = 1e-5f + 0.05f * softplus_f(Cc + x21);
        *reinterpret_cast<float2*>(&out[((size_t)(b0 + m16) * GAMMA + 27) * 2]) =
            make_float2(x20, sc);
    }
}

extern "C" void kernel_launch(void* const* d_in, const int* in_sizes, int n_in,
                              void* d_out, int out_size, void* d_ws, size_t ws_size,
                              hipStream_t stream) {
    const float* inp    = (const float*)d_in[0];
    const float* Kw     = (const float*)d_in[1];
    const float* Rw     = (const float*)d_in[2];
    const float* bias   = (const float*)d_in[3];
    const float* dv_loc = (const float*)d_in[4];
    const float* dv_rho = (const float*)d_in[5];
    const float* dv_eps = (const float*)d_in[6];
    const float* samp   = (const float*)d_in[7];
    float* out = (float*)d_out;
    const int B = in_sizes[0] / 49;   // 8192
    dim3 grid(B / TB), block(NT);
    hipLaunchKernelGGL(fib_rnn_kernel, grid, block, 0, stream,
                       inp, Kw, Rw, bias, dv_loc, dv_rho, dv_eps, samp, out, B);
}

// Round 8
// 184.003 us; speedup vs baseline: 1.8290x; 1.3310x over previous
//
#include <hip/hip_runtime.h>
#include <math.h>

#define U 128
#define GAMMA 28
#define TB 16        // batch rows per block (one MFMA tile N-dim)
#define NT 512       // 8 waves
#define NSTEPS 75    // 48 encoder + 27 feedback
#define HSTR 136     // halves per hA row: 128 + 8 pad (272 B, 16B-aligned, odd*4 dwords)
#define ESTR 260     // floats per wfin row: 258 -> 260 (1040 B, 16B-aligned)

typedef _Float16 half8 __attribute__((ext_vector_type(8)));
typedef _Float16 half4 __attribute__((ext_vector_type(4)));
typedef float floatx4 __attribute__((ext_vector_type(4)));

// v_rcp_f32-based: 1 trans + 1 add vs the ~8-slot IEEE divide expansion
__device__ __forceinline__ float sigmoid_f(float x) {
    return __builtin_amdgcn_rcpf(1.0f + __expf(-x));
}
__device__ __forceinline__ float tanh_f(float x) {
    // tanh(x) = 2*sigmoid(2x) - 1
    return fmaf(2.0f, __builtin_amdgcn_rcpf(1.0f + __expf(-2.0f * x)), -1.0f);
}
__device__ __forceinline__ float softplus_f(float x) {
    return fmaxf(x, 0.0f) + __logf(1.0f + __expf(-fabsf(x)));
}

__global__ __launch_bounds__(NT, 4) void fib_rnn_kernel(
    const float* __restrict__ inp,      // (B,49,1)
    const float* __restrict__ Kw,       // (1,384)
    const float* __restrict__ Rw,       // (128,384)
    const float* __restrict__ bias,     // (2,384)
    const float* __restrict__ dv_loc,   // (258)
    const float* __restrict__ dv_rho,   // (258)
    const float* __restrict__ dv_eps,   // (28,258)
    const float* __restrict__ samp,     // (27,B,1)
    float* __restrict__ out,            // (B,28,2)
    int B)
{
    // h[batch][k] fp16, double-buffered, row-major with padded stride
    __shared__ __align__(16) _Float16 hA[2][TB * HSTR];
    __shared__ __align__(16) float wfin[GAMMA * ESTR];   // per-step dense weights [s][2j+n]
    __shared__ float in_lds[TB * 49];
    __shared__ float samp_lds[27 * TB];
    __shared__ float wsum[2][8][TB][2];                  // [parity][wave][row][n]
    __shared__ float epsB[GAMMA][2];

    const int tid  = threadIdx.x;
    const int wv   = tid >> 6;          // wave 0..7
    const int lane = tid & 63;
    const int q    = lane >> 4;         // quad 0..3
    const int m16  = lane & 15;         // this lane's batch row
    const int j0   = wv * 16 + q * 4;   // first of this lane's 4 gate columns
    const int b0   = blockIdx.x * TB;

    const float Cc = 0.5413248546f;     // log(expm1(1))

    // ---- one-time staging
    for (int i = tid; i < TB * 48; i += NT) {
        int bl = i / 48, tt = i - bl * 48;
        in_lds[bl * 49 + tt] = inp[(size_t)(b0 + bl) * 49 + tt];
    }
    for (int i = tid; i < 2 * TB * HSTR; i += NT) (&hA[0][0])[i] = (_Float16)0.f;
    for (int i = tid; i < GAMMA * 258; i += NT) {
        int s = i / 258, t = i - 258 * s;
        float v = dv_eps[i];
        if (t < 256) {
            float sc = 1e-5f + 0.02f * softplus_f(Cc + dv_rho[t]);
            wfin[s * ESTR + t] = fmaf(sc, v, dv_loc[t]);
        } else {
            epsB[s][t - 256] = v;
        }
    }
    for (int i = tid; i < 27 * TB; i += NT) {
        int s = i >> 4, bl = i & 15;
        samp_lds[i] = samp[(size_t)s * B + b0 + bl];
    }

    // ---- stationary R^T fragments (A operand, fp16). Wave wv: tiles {wv, wv+8, wv+16}
    // A[m=lane&15][k=q*8+e+kt*32] = R[k][tile*16+m16]
    half8 Rb[3][4];
    {
        const int tiles[3] = {wv, wv + 8, wv + 16};
        #pragma unroll
        for (int t = 0; t < 3; ++t) {
            const int c = tiles[t] * 16 + m16;
            #pragma unroll
            for (int kt = 0; kt < 4; ++kt) {
                #pragma unroll
                for (int e = 0; e < 8; ++e)
                    Rb[t][kt][e] = (_Float16)Rw[(size_t)(kt * 32 + q * 8 + e) * 384 + c];
            }
        }
    }

    // per-lane gate constants for columns j0..j0+3
    float Kz4[4], Kr4[4], Kh4[4], bz4[4], br4[4], bhx4[4], bhh4[4];
    #pragma unroll
    for (int i = 0; i < 4; ++i) {
        const int j = j0 + i;
        Kz4[i]  = Kw[j]; Kr4[i] = Kw[j + U]; Kh4[i] = Kw[j + 2 * U];
        bz4[i]  = bias[j]         + bias[384 + j];
        br4[i]  = bias[j + U]     + bias[384 + j + U];
        bhx4[i] = bias[j + 2 * U];
        bhh4[i] = bias[384 + j + 2 * U];
    }
    const float wbl0 = dv_loc[256], wbl1 = dv_loc[257];
    const float wbs0 = 1e-5f + 0.02f * softplus_f(Cc + dv_rho[256]);
    const float wbs1 = 1e-5f + 0.02f * softplus_f(Cc + dv_rho[257]);

    float hprev[4] = {0.f, 0.f, 0.f, 0.f};   // h state: row m16, cols j0..j0+3

    __syncthreads();

    int cur = 0;
    for (int step = 0; step < NSTEPS; ++step) {
        // ---- recurrent matmul: preact[384][16] = R^T @ h^T   (A=R^T stationary, B=h)
        floatx4 acc[3];
        #pragma unroll
        for (int t = 0; t < 3; ++t) acc[t] = (floatx4){0.f, 0.f, 0.f, 0.f};
        #pragma unroll
        for (int kt = 0; kt < 4; ++kt) {
            const half8 Bh = *reinterpret_cast<const half8*>(&hA[cur][m16 * HSTR + kt * 32 + q * 8]);
            #pragma unroll
            for (int t = 0; t < 3; ++t)
                acc[t] = __builtin_amdgcn_mfma_f32_16x16x32_f16(Rb[t][kt], Bh, acc[t], 0, 0, 0);
        }

        // ---- phase A (fb): finish previous step's dense_var; produce this lane's y
        float yv = 0.f;
        if (step >= 48) {
            const int sp = step - 48;
            const int pb = sp & 1;
            float sx = 0.f, sy = 0.f;
            #pragma unroll
            for (int w = 0; w < 8; ++w) {
                const float2 f = *reinterpret_cast<const float2*>(&wsum[pb][w][m16][0]);
                sx += f.x; sy += f.y;
            }
            const float x20 = sx + fmaf(wbs0, epsB[sp][0], wbl0);
            const float x21 = sy + fmaf(wbs1, epsB[sp][1], wbl1);
            const float sc  = 1e-5f + 0.05f * softplus_f(Cc + x21);
            yv = fmaf(sc, samp_lds[sp * 16 + m16], x20);
            if (wv == 0 && q == 0)
                *reinterpret_cast<float2*>(&out[((size_t)(b0 + m16) * GAMMA + sp) * 2]) =
                    make_float2(x20, sc);
        }

        // ---- gates: lane owns (row m16, cols j0..j0+3); fp32 state in regs
        const float x = (step < 48) ? in_lds[m16 * 49 + step] : yv;
        float hn[4];
        #pragma unroll
        for (int i = 0; i < 4; ++i) {
            const float z  = sigmoid_f(acc[0][i] + fmaf(x, Kz4[i], bz4[i]));
            const float r  = sigmoid_f(acc[1][i] + fmaf(x, Kr4[i], br4[i]));
            const float hh = tanh_f(fmaf(x, Kh4[i], bhx4[i]) + r * (acc[2][i] + bhh4[i]));
            hn[i] = z * hprev[i] + (1.f - z) * hh;
            hprev[i] = hn[i];
        }
        // one contiguous 8B store into the other h buffer
        half4 hp;
        #pragma unroll
        for (int i = 0; i < 4; ++i) hp[i] = (_Float16)hn[i];
        *reinterpret_cast<half4*>(&hA[cur ^ 1][m16 * HSTR + j0]) = hp;

        // ---- dense_var partials for this step (consumed next step in phase A)
        if (step >= 47) {
            const int s = step - 47;
            const float4 wa = *reinterpret_cast<const float4*>(&wfin[s * ESTR + 2 * j0]);
            const float4 wb = *reinterpret_cast<const float4*>(&wfin[s * ESTR + 2 * j0 + 4]);
            float pv0 = hn[0] * wa.x + hn[1] * wa.z + hn[2] * wb.x + hn[3] * wb.z;
            float pv1 = hn[0] * wa.y + hn[1] * wa.w + hn[2] * wb.y + hn[3] * wb.w;
            pv0 += __shfl_xor(pv0, 16, 64);  pv1 += __shfl_xor(pv1, 16, 64);
            pv0 += __shfl_xor(pv0, 32, 64);  pv1 += __shfl_xor(pv1, 32, 64);
            if (q == 0)
                *reinterpret_cast<float2*>(&wsum[s & 1][wv][m16][0]) = make_float2(pv0, pv1);
        }

        __syncthreads();   // the ONLY barrier: h[nxt] + wsum(s) visible
        cur ^= 1;
    }

    // ---- final output s = 27 (parity 1)
    if (wv == 0 && q == 0) {
        float sx = 0.f, sy = 0.f;
        #pragma unroll
        for (int w = 0; w < 8; ++w) {
            const float2 f = *reinterpret_cast<const float2*>(&wsum[1][w][m16][0]);
            sx += f.x; sy += f.y;
        }
        const float x20 = sx + fmaf(wbs0, epsB[27][0], wbl0);
        const float x21 = sy + fmaf(wbs1, epsB[27][1], wbl1);
        const float sc  = 1e-5f + 0.05f * softplus_f(Cc + x21);
        *reinterpret_cast<float2*>(&out[((size_t)(b0 + m16) * GAMMA + 27) * 2]) =
            make_float2(x20, sc);
    }
}

extern "C" void kernel_launch(void* const* d_in, const int* in_sizes, int n_in,
                              void* d_out, int out_size, void* d_ws, size_t ws_size,
                              hipStream_t stream) {
    const float* inp    = (const float*)d_in[0];
    const float* Kw     = (const float*)d_in[1];
    const float* Rw     = (const float*)d_in[2];
    const float* bias   = (const float*)d_in[3];
    const float* dv_loc = (const float*)d_in[4];
    const float* dv_rho = (const float*)d_in[5];
    const float* dv_eps = (const float*)d_in[6];
    const float* samp   = (const float*)d_in[7];
    float* out = (float*)d_out;
    const int B = in_sizes[0] / 49;   // 8192
    dim3 grid(B / TB), block(NT);
    hipLaunchKernelGGL(fib_rnn_kernel, grid, block, 0, stream,
                       inp, Kw, Rw, bias, dv_loc, dv_rho, dv_eps, samp, out, B);
}